// Round 10
// baseline (77.462 us; speedup 1.0000x reference)
//
#include <hip/hip_runtime.h>
#include <hip/hip_fp16.h>
#include <math.h>

// Problem constants (from reference)
#define B_SZ 8192
#define L_SZ 50
#define D_SZ 128
#define C_SZ 256        // output cols of W_cpr
#define K_SZ 256        // = 2*D, GEMM K
#define R_SZ 7
#define V_SZ 100000

// ---------------------------------------------------------------------------
// Kernel A: convert emb f32 [V][128] -> fp16 table in ws. 77 MB streaming.
// ---------------------------------------------------------------------------
__global__ __launch_bounds__(256) void k_convert(const float* __restrict__ src,
                                                 __half* __restrict__ dst,
                                                 int n4) {
    int i = blockIdx.x * 256 + threadIdx.x;
    if (i >= n4) return;
    float4 v = ((const float4*)src)[i];
    union { __half2 h[2]; uint2 u; } pk;
    pk.h[0].x = __float2half_rn(v.x); pk.h[0].y = __float2half_rn(v.y);
    pk.h[1].x = __float2half_rn(v.z); pk.h[1].y = __float2half_rn(v.w);
    ((uint2*)dst)[i] = pk.u;
}

// ---------------------------------------------------------------------------
// Kernel B: transpose W_cpr [C][K] -> Wt [K][C], LDS-tiled. 256 KB, ~2 us.
// ---------------------------------------------------------------------------
__global__ __launch_bounds__(256) void k_transpose(const float* __restrict__ W,
                                                   float* __restrict__ Wt) {
    __shared__ float t[32][33];
    const int tx = threadIdx.x & 31;
    const int ty = threadIdx.x >> 5;  // 0..7
    const int k0 = blockIdx.x * 32;
    const int c0 = blockIdx.y * 32;
#pragma unroll
    for (int i = 0; i < 32; i += 8)
        t[ty + i][tx] = W[(size_t)(c0 + ty + i) * K_SZ + k0 + tx];
    __syncthreads();
#pragma unroll
    for (int i = 0; i < 32; i += 8)
        Wt[(size_t)(k0 + ty + i) * C_SZ + c0 + tx] = t[tx][ty + i];
}

// ---------------------------------------------------------------------------
// Gather kernel (fp16 table): 1 batch row per WAVE, 4 waves/block, grid 2048.
// Full-residency config: 8192 waves = 32 waves/CU (VGPR kept <=64 via
// __launch_bounds__(256,8); body is small, no spill). Per iteration a wave
// issues 2 unconditional 1 KB loads (4 tokens per side via 16-lane groups)
// from the compacted token lists -> maximal lines-in-flight per CU.
// Output: X[row][0:128]=left sum, [128:256]=right sum (f32).
// ---------------------------------------------------------------------------
__global__ __launch_bounds__(256, 8) void k_gather_h(
    const int* __restrict__ ltok, const int* __restrict__ rtok,
    const int* __restrict__ lmask, const int* __restrict__ rmask,
    const __half* __restrict__ E16, float* __restrict__ X) {

    __shared__ int ctok[4][2][52];

    const int wave = threadIdx.x >> 6;
    const int lane = threadIdx.x & 63;
    const int grp = lane >> 4;   // 16-lane group 0..3 (token slot within quad)
    const int sub = lane & 15;   // float4 slot within a 256 B fp16 row
    const int row = blockIdx.x * 4 + wave;

    int lt = 0, rt = 0, lm = 0, rm = 0;
    if (lane < L_SZ) {
        const size_t o = (size_t)row * L_SZ + lane;
        lt = ltok[o]; lm = lmask[o]; rt = rtok[o]; rm = rmask[o];
    }
    const unsigned long long ltm = (1ULL << lane) - 1;
    const unsigned long long balL = __ballot(lm != 0);
    const unsigned long long balR = __ballot(rm != 0);
    const int cntL = __popcll(balL);
    const int cntR = __popcll(balR);
    if (lm) ctok[wave][0][__popcll(balL & ltm)] = lt;
    if (rm) ctok[wave][1][__popcll(balR & ltm)] = rt;
    if (lane == 0) {
        if (cntL == 0) ctok[wave][0][0] = 0;
        if (cntR == 0) ctok[wave][1][0] = 0;
    }
    // (ctok is wave-private; in-wave LDS RAW ordering handled by lgkmcnt)

    const float4* E = (const float4*)E16;  // [V][16] float4 (8 halves each)
    float aL[8] = {0}, aR[8] = {0};
    const int maxc = max(cntL, cntR);
    const int nit = (maxc + 3) >> 2;

    for (int it = 0; it < nit; ++it) {
        const int idx = it * 4 + grp;
#define GATH(side, cnt, A)                                                \
        {                                                                 \
            int ii = min(idx, cnt - 1); ii = (ii < 0) ? 0 : ii;           \
            const int t_ = ctok[wave][side][ii];                          \
            const float sc = (idx < cnt) ? 1.f : 0.f;                     \
            const float4 ev = E[((size_t)t_ << 4) + sub];                 \
            const __half2* hp = (const __half2*)&ev;                      \
            _Pragma("unroll")                                             \
            for (int q = 0; q < 4; ++q) {                                 \
                A[2 * q]     = fmaf(sc, __half2float(hp[q].x), A[2 * q]);       \
                A[2 * q + 1] = fmaf(sc, __half2float(hp[q].y), A[2 * q + 1]);   \
            }                                                             \
        }
        GATH(0, cntL, aL)
        GATH(1, cntR, aR)
#undef GATH
    }

    // reduce across the 4 groups (lanes sharing `sub`)
#pragma unroll
    for (int j = 0; j < 8; ++j) {
        aL[j] += __shfl_xor(aL[j], 16);
        aL[j] += __shfl_xor(aL[j], 32);
        aR[j] += __shfl_xor(aR[j], 16);
        aR[j] += __shfl_xor(aR[j], 32);
    }

    // store: group 0 writes left half, group 1 writes right half
    float4* Xo = (float4*)(X + (size_t)row * K_SZ);
    if (grp == 0) {
        Xo[sub * 2 + 0] = make_float4(aL[0], aL[1], aL[2], aL[3]);
        Xo[sub * 2 + 1] = make_float4(aL[4], aL[5], aL[6], aL[7]);
    } else if (grp == 1) {
        Xo[32 + sub * 2 + 0] = make_float4(aR[0], aR[1], aR[2], aR[3]);
        Xo[32 + sub * 2 + 1] = make_float4(aR[4], aR[5], aR[6], aR[7]);
    }
}

// ---------------------------------------------------------------------------
// Gather kernel (f32 table fallback, no convert): 1 row/wave, 2x 1KB loads
// per iteration covering 2 tokens per side (32-lane halves).
// ---------------------------------------------------------------------------
__global__ __launch_bounds__(256, 8) void k_gather_f(
    const int* __restrict__ ltok, const int* __restrict__ rtok,
    const int* __restrict__ lmask, const int* __restrict__ rmask,
    const float* __restrict__ emb, float* __restrict__ X) {

    __shared__ int ctok[4][2][52];

    const int wave = threadIdx.x >> 6;
    const int lane = threadIdx.x & 63;
    const int grp = lane >> 5;   // 32-lane half 0..1 (token slot within pair)
    const int sub = lane & 31;   // float4 slot within a 512 B f32 row
    const int row = blockIdx.x * 4 + wave;

    int lt = 0, rt = 0, lm = 0, rm = 0;
    if (lane < L_SZ) {
        const size_t o = (size_t)row * L_SZ + lane;
        lt = ltok[o]; lm = lmask[o]; rt = rtok[o]; rm = rmask[o];
    }
    const unsigned long long ltm = (1ULL << lane) - 1;
    const unsigned long long balL = __ballot(lm != 0);
    const unsigned long long balR = __ballot(rm != 0);
    const int cntL = __popcll(balL);
    const int cntR = __popcll(balR);
    if (lm) ctok[wave][0][__popcll(balL & ltm)] = lt;
    if (rm) ctok[wave][1][__popcll(balR & ltm)] = rt;
    if (lane == 0) {
        if (cntL == 0) ctok[wave][0][0] = 0;
        if (cntR == 0) ctok[wave][1][0] = 0;
    }

    const float4* E = (const float4*)emb;  // [V][32] float4
    float aL[4] = {0}, aR[4] = {0};
    const int maxc = max(cntL, cntR);
    const int nit = (maxc + 1) >> 1;

    for (int it = 0; it < nit; ++it) {
        const int idx = it * 2 + grp;
#define GATH(side, cnt, A)                                                \
        {                                                                 \
            int ii = min(idx, cnt - 1); ii = (ii < 0) ? 0 : ii;           \
            const int t_ = ctok[wave][side][ii];                          \
            const float sc = (idx < cnt) ? 1.f : 0.f;                     \
            const float4 ev = E[((size_t)t_ << 5) + sub];                 \
            A[0] = fmaf(sc, ev.x, A[0]); A[1] = fmaf(sc, ev.y, A[1]);     \
            A[2] = fmaf(sc, ev.z, A[2]); A[3] = fmaf(sc, ev.w, A[3]);     \
        }
        GATH(0, cntL, aL)
        GATH(1, cntR, aR)
#undef GATH
    }

#pragma unroll
    for (int j = 0; j < 4; ++j) {
        aL[j] += __shfl_xor(aL[j], 32);
        aR[j] += __shfl_xor(aR[j], 32);
    }

    float4* Xo = (float4*)(X + (size_t)row * K_SZ);
    if (grp == 0) {
        Xo[sub] = make_float4(aL[0], aL[1], aL[2], aL[3]);
    } else {
        Xo[32 + sub] = make_float4(aR[0], aR[1], aR[2], aR[3]);
    }
}

// ---------------------------------------------------------------------------
// MLP kernel: h = LeakyReLU(X @ Wt + b); logits = h @ W_sm^T + b_sm;
// out = log_softmax. R6-proven shape: grid 256, 512 threads, BR=32 rows,
// 64 col-groups x 8 row-groups, acc[4][4]; W float4 coalesced from Wt;
// X read as wave-uniform global float4 (L1/scalar-cached).
// ---------------------------------------------------------------------------
__global__ __launch_bounds__(512, 2) void k_mlp(
    const float* __restrict__ X, const float* __restrict__ Wt,
    const float* __restrict__ b_cpr, const float* __restrict__ W_sm,
    const float* __restrict__ b_sm, float* __restrict__ out) {

    __shared__ float h_lds[32][C_SZ + 4];    // 33.3 KB
    __shared__ float part[32][R_SZ][2];
    __shared__ float l_lds[32][R_SZ];

    const int tid = threadIdx.x;
    const int row0 = blockIdx.x * 32;
    const int cc = (tid & 63) * 4;        // 4 output cols
    const int rr = (tid >> 6) * 4;        // 4 rows

    float acc[4][4] = {{0.f}};
    const float* Xb = X + (size_t)(row0 + rr) * K_SZ;

#pragma unroll 2
    for (int k = 0; k < K_SZ; k += 4) {
        float4 w0 = *(const float4*)&Wt[(k + 0) * C_SZ + cc];
        float4 w1 = *(const float4*)&Wt[(k + 1) * C_SZ + cc];
        float4 w2 = *(const float4*)&Wt[(k + 2) * C_SZ + cc];
        float4 w3 = *(const float4*)&Wt[(k + 3) * C_SZ + cc];
        float ws[4][4] = {{w0.x, w0.y, w0.z, w0.w}, {w1.x, w1.y, w1.z, w1.w},
                          {w2.x, w2.y, w2.z, w2.w}, {w3.x, w3.y, w3.z, w3.w}};
#pragma unroll
        for (int i = 0; i < 4; ++i) {
            float4 xv = *(const float4*)&Xb[(size_t)i * K_SZ + k];  // uniform
            float xs[4] = {xv.x, xv.y, xv.z, xv.w};
#pragma unroll
            for (int kk = 0; kk < 4; ++kk) {
#pragma unroll
                for (int j = 0; j < 4; ++j)
                    acc[i][j] = fmaf(xs[kk], ws[kk][j], acc[i][j]);
            }
        }
    }

    // bias + LeakyReLU -> LDS
#pragma unroll
    for (int i = 0; i < 4; ++i) {
        float4 hv;
        float* hp = (float*)&hv;
#pragma unroll
        for (int j = 0; j < 4; ++j) {
            float h = acc[i][j] + b_cpr[cc + j];
            hp[j] = (h >= 0.f) ? h : 0.01f * h;
        }
        *(float4*)&h_lds[rr + i][cc] = hv;
    }
    __syncthreads();

    // head: K-split partial dots (2 chunks of 128)
    if (tid < 32 * R_SZ * 2) {            // 448 threads: (bl, r, chunk)
        const int chunk = tid & 1;
        const int rh = (tid >> 1) % R_SZ;
        const int bl = tid / (R_SZ * 2);
        const float* wr = W_sm + rh * C_SZ;
        const int c0 = chunk * 128;
        float s = 0.f;
#pragma unroll
        for (int c = 0; c < 128; c += 4) {
            float4 hv = *(const float4*)&h_lds[bl][c0 + c];
            s = fmaf(hv.x, wr[c0 + c + 0], s);
            s = fmaf(hv.y, wr[c0 + c + 1], s);
            s = fmaf(hv.z, wr[c0 + c + 2], s);
            s = fmaf(hv.w, wr[c0 + c + 3], s);
        }
        part[bl][rh][chunk] = s;
    }
    __syncthreads();

    if (tid < 32 * R_SZ) {                // 224 threads: combine + bias
        const int bl = tid / R_SZ;
        const int rh = tid % R_SZ;
        l_lds[bl][rh] = part[bl][rh][0] + part[bl][rh][1] + b_sm[rh];
    }
    __syncthreads();

    // log-softmax over R=7
    if (tid < 32) {
        float m = -INFINITY;
#pragma unroll
        for (int rh = 0; rh < R_SZ; ++rh) m = fmaxf(m, l_lds[tid][rh]);
        float se = 0.f;
#pragma unroll
        for (int rh = 0; rh < R_SZ; ++rh) se += expf(l_lds[tid][rh] - m);
        const float lse = m + logf(se);
        const size_t ob = (size_t)(row0 + tid) * R_SZ;
#pragma unroll
        for (int rh = 0; rh < R_SZ; ++rh) out[ob + rh] = l_lds[tid][rh] - lse;
    }
}

// ---------------------------------------------------------------------------
extern "C" void kernel_launch(void* const* d_in, const int* in_sizes, int n_in,
                              void* d_out, int out_size, void* d_ws, size_t ws_size,
                              hipStream_t stream) {
    const int* ltok = (const int*)d_in[0];
    const int* rtok = (const int*)d_in[1];
    const int* lmask = (const int*)d_in[2];
    const int* rmask = (const int*)d_in[3];
    const float* emb = (const float*)d_in[4];
    const float* W_cpr = (const float*)d_in[5];
    const float* b_cpr = (const float*)d_in[6];
    const float* W_sm = (const float*)d_in[7];
    const float* b_sm = (const float*)d_in[8];
    float* out = (float*)d_out;

    const size_t E16_BYTES = (size_t)V_SZ * D_SZ * sizeof(__half);  // 25.6 MB
    const size_t WT_BYTES = (size_t)K_SZ * C_SZ * sizeof(float);    // 256 KB
    const size_t X_BYTES = (size_t)B_SZ * K_SZ * sizeof(float);     // 8 MB

    if (ws_size >= E16_BYTES + WT_BYTES + X_BYTES) {
        // fp16-table path
        __half* E16 = (__half*)d_ws;
        float* Wt = (float*)((char*)d_ws + E16_BYTES);
        float* X = (float*)((char*)d_ws + E16_BYTES + WT_BYTES);
        const int n4 = V_SZ * D_SZ / 4;
        k_transpose<<<dim3(K_SZ / 32, C_SZ / 32), 256, 0, stream>>>(W_cpr, Wt);
        k_convert<<<(n4 + 255) / 256, 256, 0, stream>>>(emb, E16, n4);
        k_gather_h<<<B_SZ / 4, 256, 0, stream>>>(ltok, rtok, lmask, rmask,
                                                 E16, X);
        k_mlp<<<B_SZ / 32, 512, 0, stream>>>(X, Wt, b_cpr, W_sm, b_sm, out);
    } else {
        // f32-direct path (smaller ws footprint, no convert)
        float* Wt = (float*)d_ws;
        float* X = (float*)((char*)d_ws + WT_BYTES);
        k_transpose<<<dim3(K_SZ / 32, C_SZ / 32), 256, 0, stream>>>(W_cpr, Wt);
        k_gather_f<<<B_SZ / 4, 256, 0, stream>>>(ltok, rtok, lmask, rmask,
                                                 emb, X);
        k_mlp<<<B_SZ / 32, 512, 0, stream>>>(X, Wt, b_cpr, W_sm, b_sm, out);
    }
}

// Round 11
// 65.301 us; speedup vs baseline: 1.1862x; 1.1862x over previous
//
#include <hip/hip_runtime.h>
#include <hip/hip_fp16.h>
#include <math.h>

// Problem constants (from reference)
#define B_SZ 8192
#define L_SZ 50
#define D_SZ 128
#define C_SZ 256        // output cols of W_cpr
#define K_SZ 256        // = 2*D, GEMM K
#define R_SZ 7
#define V_SZ 100000

// ---------------------------------------------------------------------------
// Kernel A: convert emb f32 [V][128] -> fp16 table in ws. 77 MB streaming.
// ---------------------------------------------------------------------------
__global__ __launch_bounds__(256) void k_convert(const float* __restrict__ src,
                                                 __half* __restrict__ dst,
                                                 int n4) {
    int i = blockIdx.x * 256 + threadIdx.x;
    if (i >= n4) return;
    float4 v = ((const float4*)src)[i];
    union { __half2 h[2]; uint2 u; } pk;
    pk.h[0].x = __float2half_rn(v.x); pk.h[0].y = __float2half_rn(v.y);
    pk.h[1].x = __float2half_rn(v.z); pk.h[1].y = __float2half_rn(v.w);
    ((uint2*)dst)[i] = pk.u;
}

// ---------------------------------------------------------------------------
// Kernel B: transpose W_cpr [C][K] -> Wt [K][C], LDS-tiled. 256 KB, ~2 us.
// ---------------------------------------------------------------------------
__global__ __launch_bounds__(256) void k_transpose(const float* __restrict__ W,
                                                   float* __restrict__ Wt) {
    __shared__ float t[32][33];
    const int tx = threadIdx.x & 31;
    const int ty = threadIdx.x >> 5;  // 0..7
    const int k0 = blockIdx.x * 32;
    const int c0 = blockIdx.y * 32;
#pragma unroll
    for (int i = 0; i < 32; i += 8)
        t[ty + i][tx] = W[(size_t)(c0 + ty + i) * K_SZ + k0 + tx];
    __syncthreads();
#pragma unroll
    for (int i = 0; i < 32; i += 8)
        Wt[(size_t)(k0 + ty + i) * C_SZ + c0 + tx] = t[tx][ty + i];
}

// ---------------------------------------------------------------------------
// Gather kernel (fp16 table): 1 batch row per WAVE, 4 waves/block, grid 2048.
// (Unchanged from R10 — delivered ~19 us at full residency.)
// ---------------------------------------------------------------------------
__global__ __launch_bounds__(256, 8) void k_gather_h(
    const int* __restrict__ ltok, const int* __restrict__ rtok,
    const int* __restrict__ lmask, const int* __restrict__ rmask,
    const __half* __restrict__ E16, float* __restrict__ X) {

    __shared__ int ctok[4][2][52];

    const int wave = threadIdx.x >> 6;
    const int lane = threadIdx.x & 63;
    const int grp = lane >> 4;   // 16-lane group 0..3 (token slot within quad)
    const int sub = lane & 15;   // float4 slot within a 256 B fp16 row
    const int row = blockIdx.x * 4 + wave;

    int lt = 0, rt = 0, lm = 0, rm = 0;
    if (lane < L_SZ) {
        const size_t o = (size_t)row * L_SZ + lane;
        lt = ltok[o]; lm = lmask[o]; rt = rtok[o]; rm = rmask[o];
    }
    const unsigned long long ltm = (1ULL << lane) - 1;
    const unsigned long long balL = __ballot(lm != 0);
    const unsigned long long balR = __ballot(rm != 0);
    const int cntL = __popcll(balL);
    const int cntR = __popcll(balR);
    if (lm) ctok[wave][0][__popcll(balL & ltm)] = lt;
    if (rm) ctok[wave][1][__popcll(balR & ltm)] = rt;
    if (lane == 0) {
        if (cntL == 0) ctok[wave][0][0] = 0;
        if (cntR == 0) ctok[wave][1][0] = 0;
    }

    const float4* E = (const float4*)E16;  // [V][16] float4 (8 halves each)
    float aL[8] = {0}, aR[8] = {0};
    const int maxc = max(cntL, cntR);
    const int nit = (maxc + 3) >> 2;

    for (int it = 0; it < nit; ++it) {
        const int idx = it * 4 + grp;
#define GATH(side, cnt, A)                                                \
        {                                                                 \
            int ii = min(idx, cnt - 1); ii = (ii < 0) ? 0 : ii;           \
            const int t_ = ctok[wave][side][ii];                          \
            const float sc = (idx < cnt) ? 1.f : 0.f;                     \
            const float4 ev = E[((size_t)t_ << 4) + sub];                 \
            const __half2* hp = (const __half2*)&ev;                      \
            _Pragma("unroll")                                             \
            for (int q = 0; q < 4; ++q) {                                 \
                A[2 * q]     = fmaf(sc, __half2float(hp[q].x), A[2 * q]);       \
                A[2 * q + 1] = fmaf(sc, __half2float(hp[q].y), A[2 * q + 1]);   \
            }                                                             \
        }
        GATH(0, cntL, aL)
        GATH(1, cntR, aR)
#undef GATH
    }

#pragma unroll
    for (int j = 0; j < 8; ++j) {
        aL[j] += __shfl_xor(aL[j], 16);
        aL[j] += __shfl_xor(aL[j], 32);
        aR[j] += __shfl_xor(aR[j], 16);
        aR[j] += __shfl_xor(aR[j], 32);
    }

    float4* Xo = (float4*)(X + (size_t)row * K_SZ);
    if (grp == 0) {
        Xo[sub * 2 + 0] = make_float4(aL[0], aL[1], aL[2], aL[3]);
        Xo[sub * 2 + 1] = make_float4(aL[4], aL[5], aL[6], aL[7]);
    } else if (grp == 1) {
        Xo[32 + sub * 2 + 0] = make_float4(aR[0], aR[1], aR[2], aR[3]);
        Xo[32 + sub * 2 + 1] = make_float4(aR[4], aR[5], aR[6], aR[7]);
    }
}

// ---------------------------------------------------------------------------
// Gather kernel (f32 table fallback, no convert).
// ---------------------------------------------------------------------------
__global__ __launch_bounds__(256, 8) void k_gather_f(
    const int* __restrict__ ltok, const int* __restrict__ rtok,
    const int* __restrict__ lmask, const int* __restrict__ rmask,
    const float* __restrict__ emb, float* __restrict__ X) {

    __shared__ int ctok[4][2][52];

    const int wave = threadIdx.x >> 6;
    const int lane = threadIdx.x & 63;
    const int grp = lane >> 5;   // 32-lane half 0..1
    const int sub = lane & 31;   // float4 slot within a 512 B f32 row
    const int row = blockIdx.x * 4 + wave;

    int lt = 0, rt = 0, lm = 0, rm = 0;
    if (lane < L_SZ) {
        const size_t o = (size_t)row * L_SZ + lane;
        lt = ltok[o]; lm = lmask[o]; rt = rtok[o]; rm = rmask[o];
    }
    const unsigned long long ltm = (1ULL << lane) - 1;
    const unsigned long long balL = __ballot(lm != 0);
    const unsigned long long balR = __ballot(rm != 0);
    const int cntL = __popcll(balL);
    const int cntR = __popcll(balR);
    if (lm) ctok[wave][0][__popcll(balL & ltm)] = lt;
    if (rm) ctok[wave][1][__popcll(balR & ltm)] = rt;
    if (lane == 0) {
        if (cntL == 0) ctok[wave][0][0] = 0;
        if (cntR == 0) ctok[wave][1][0] = 0;
    }

    const float4* E = (const float4*)emb;  // [V][32] float4
    float aL[4] = {0}, aR[4] = {0};
    const int maxc = max(cntL, cntR);
    const int nit = (maxc + 1) >> 1;

    for (int it = 0; it < nit; ++it) {
        const int idx = it * 2 + grp;
#define GATH(side, cnt, A)                                                \
        {                                                                 \
            int ii = min(idx, cnt - 1); ii = (ii < 0) ? 0 : ii;           \
            const int t_ = ctok[wave][side][ii];                          \
            const float sc = (idx < cnt) ? 1.f : 0.f;                     \
            const float4 ev = E[((size_t)t_ << 5) + sub];                 \
            A[0] = fmaf(sc, ev.x, A[0]); A[1] = fmaf(sc, ev.y, A[1]);     \
            A[2] = fmaf(sc, ev.z, A[2]); A[3] = fmaf(sc, ev.w, A[3]);     \
        }
        GATH(0, cntL, aL)
        GATH(1, cntR, aR)
#undef GATH
    }

#pragma unroll
    for (int j = 0; j < 4; ++j) {
        aL[j] += __shfl_xor(aL[j], 32);
        aR[j] += __shfl_xor(aR[j], 32);
    }

    float4* Xo = (float4*)(X + (size_t)row * K_SZ);
    if (grp == 0) {
        Xo[sub] = make_float4(aL[0], aL[1], aL[2], aL[3]);
    } else {
        Xo[32 + sub] = make_float4(aR[0], aR[1], aR[2], aR[3]);
    }
}

// ---------------------------------------------------------------------------
// MLP kernel v3: W staged through LDS in 64-row K-tiles.
// grid 256 x 512 threads, BR=32 rows. Per block: X (32 KB) staged once,
// Wt in 4 x 64 KB tiles; FMA reads W via ds_read_b128 (throughput ~12cy,
// no miss path) instead of L1-missing global loads. Per-CU W delivery:
// one 256 KB global read per block (vs 8 wave-private 256 KB L1 streams).
// ---------------------------------------------------------------------------
#define KT 64
__global__ __launch_bounds__(512, 2) void k_mlp(
    const float* __restrict__ X, const float* __restrict__ Wt,
    const float* __restrict__ b_cpr, const float* __restrict__ W_sm,
    const float* __restrict__ b_sm, float* __restrict__ out) {

    __shared__ float Wl[KT][C_SZ];           // 64 KB W K-tile
    __shared__ float X_lds[32][K_SZ];        // 32 KB
    __shared__ float part[32][R_SZ][2];
    __shared__ float l_lds[32][R_SZ];

    const int tid = threadIdx.x;
    const int row0 = blockIdx.x * 32;
    const int cc = (tid & 63) * 4;        // 4 output cols
    const int rr = (tid >> 6) * 4;        // 4 rows

    // stage X once: 32*256 f32 = 2048 float4, 4 per thread, coalesced
    {
        const float4* Xg = (const float4*)(X + (size_t)row0 * K_SZ);
        float4* Xs = (float4*)&X_lds[0][0];
#pragma unroll
        for (int i = 0; i < 4; ++i) Xs[tid + i * 512] = Xg[tid + i * 512];
    }

    float acc[4][4] = {{0.f}};

    for (int kt = 0; kt < K_SZ / KT; ++kt) {
        // stage W tile: KT*256 f32 = 4096 float4, 8 per thread, coalesced
        {
            const float4* Wg = (const float4*)(Wt + (size_t)kt * KT * C_SZ);
            float4* Ws = (float4*)&Wl[0][0];
#pragma unroll
            for (int i = 0; i < 8; ++i) Ws[tid + i * 512] = Wg[tid + i * 512];
        }
        __syncthreads();

        const int kbase = kt * KT;
#pragma unroll 2
        for (int k = 0; k < KT; k += 4) {
            float4 w0 = *(const float4*)&Wl[k + 0][cc];
            float4 w1 = *(const float4*)&Wl[k + 1][cc];
            float4 w2 = *(const float4*)&Wl[k + 2][cc];
            float4 w3 = *(const float4*)&Wl[k + 3][cc];
            float ws[4][4] = {{w0.x, w0.y, w0.z, w0.w},
                              {w1.x, w1.y, w1.z, w1.w},
                              {w2.x, w2.y, w2.z, w2.w},
                              {w3.x, w3.y, w3.z, w3.w}};
#pragma unroll
            for (int i = 0; i < 4; ++i) {
                float4 xv = *(const float4*)&X_lds[rr + i][kbase + k];
                float xs[4] = {xv.x, xv.y, xv.z, xv.w};
#pragma unroll
                for (int kk = 0; kk < 4; ++kk) {
#pragma unroll
                    for (int j = 0; j < 4; ++j)
                        acc[i][j] = fmaf(xs[kk], ws[kk][j], acc[i][j]);
                }
            }
        }
        __syncthreads();  // protect Wl before next stage / h-write
    }

    // bias + LeakyReLU -> h (aliased onto Wl, padded rows of 260)
    float (*h_lds)[C_SZ + 4] = (float (*)[C_SZ + 4])&Wl[0][0];
#pragma unroll
    for (int i = 0; i < 4; ++i) {
        float4 hv;
        float* hp = (float*)&hv;
#pragma unroll
        for (int j = 0; j < 4; ++j) {
            float h = acc[i][j] + b_cpr[cc + j];
            hp[j] = (h >= 0.f) ? h : 0.01f * h;
        }
        *(float4*)&h_lds[rr + i][cc] = hv;
    }
    __syncthreads();

    // head: K-split partial dots (2 chunks of 128)
    if (tid < 32 * R_SZ * 2) {            // 448 threads: (bl, r, chunk)
        const int chunk = tid & 1;
        const int rh = (tid >> 1) % R_SZ;
        const int bl = tid / (R_SZ * 2);
        const float* wr = W_sm + rh * C_SZ;
        const int c0 = chunk * 128;
        float s = 0.f;
#pragma unroll
        for (int c = 0; c < 128; c += 4) {
            float4 hv = *(const float4*)&h_lds[bl][c0 + c];
            s = fmaf(hv.x, wr[c0 + c + 0], s);
            s = fmaf(hv.y, wr[c0 + c + 1], s);
            s = fmaf(hv.z, wr[c0 + c + 2], s);
            s = fmaf(hv.w, wr[c0 + c + 3], s);
        }
        part[bl][rh][chunk] = s;
    }
    __syncthreads();

    if (tid < 32 * R_SZ) {                // 224 threads: combine + bias
        const int bl = tid / R_SZ;
        const int rh = tid % R_SZ;
        l_lds[bl][rh] = part[bl][rh][0] + part[bl][rh][1] + b_sm[rh];
    }
    __syncthreads();

    // log-softmax over R=7
    if (tid < 32) {
        float m = -INFINITY;
#pragma unroll
        for (int rh = 0; rh < R_SZ; ++rh) m = fmaxf(m, l_lds[tid][rh]);
        float se = 0.f;
#pragma unroll
        for (int rh = 0; rh < R_SZ; ++rh) se += expf(l_lds[tid][rh] - m);
        const float lse = m + logf(se);
        const size_t ob = (size_t)(row0 + tid) * R_SZ;
#pragma unroll
        for (int rh = 0; rh < R_SZ; ++rh) out[ob + rh] = l_lds[tid][rh] - lse;
    }
}

// ---------------------------------------------------------------------------
extern "C" void kernel_launch(void* const* d_in, const int* in_sizes, int n_in,
                              void* d_out, int out_size, void* d_ws, size_t ws_size,
                              hipStream_t stream) {
    const int* ltok = (const int*)d_in[0];
    const int* rtok = (const int*)d_in[1];
    const int* lmask = (const int*)d_in[2];
    const int* rmask = (const int*)d_in[3];
    const float* emb = (const float*)d_in[4];
    const float* W_cpr = (const float*)d_in[5];
    const float* b_cpr = (const float*)d_in[6];
    const float* W_sm = (const float*)d_in[7];
    const float* b_sm = (const float*)d_in[8];
    float* out = (float*)d_out;

    const size_t E16_BYTES = (size_t)V_SZ * D_SZ * sizeof(__half);  // 25.6 MB
    const size_t WT_BYTES = (size_t)K_SZ * C_SZ * sizeof(float);    // 256 KB
    const size_t X_BYTES = (size_t)B_SZ * K_SZ * sizeof(float);     // 8 MB

    if (ws_size >= E16_BYTES + WT_BYTES + X_BYTES) {
        // fp16-table path
        __half* E16 = (__half*)d_ws;
        float* Wt = (float*)((char*)d_ws + E16_BYTES);
        float* X = (float*)((char*)d_ws + E16_BYTES + WT_BYTES);
        const int n4 = V_SZ * D_SZ / 4;
        k_transpose<<<dim3(K_SZ / 32, C_SZ / 32), 256, 0, stream>>>(W_cpr, Wt);
        k_convert<<<(n4 + 255) / 256, 256, 0, stream>>>(emb, E16, n4);
        k_gather_h<<<B_SZ / 4, 256, 0, stream>>>(ltok, rtok, lmask, rmask,
                                                 E16, X);
        k_mlp<<<B_SZ / 32, 512, 0, stream>>>(X, Wt, b_cpr, W_sm, b_sm, out);
    } else {
        // f32-direct path (smaller ws footprint, no convert)
        float* Wt = (float*)d_ws;
        float* X = (float*)((char*)d_ws + WT_BYTES);
        k_transpose<<<dim3(K_SZ / 32, C_SZ / 32), 256, 0, stream>>>(W_cpr, Wt);
        k_gather_f<<<B_SZ / 4, 256, 0, stream>>>(ltok, rtok, lmask, rmask,
                                                 emb, X);
        k_mlp<<<B_SZ / 32, 512, 0, stream>>>(X, Wt, b_cpr, W_sm, b_sm, out);
    }
}

// Round 12
// 51.371 us; speedup vs baseline: 1.5079x; 1.2712x over previous
//
#include <hip/hip_runtime.h>
#include <hip/hip_fp16.h>
#include <hip/hip_bf16.h>
#include <math.h>

// Problem constants (from reference)
#define B_SZ 8192
#define L_SZ 50
#define D_SZ 128
#define C_SZ 256        // output cols of W_cpr
#define K_SZ 256        // = 2*D, GEMM K
#define R_SZ 7
#define V_SZ 100000

typedef __attribute__((ext_vector_type(8))) short bf16x8;
typedef __attribute__((ext_vector_type(4))) float f32x4;

// ---------------------------------------------------------------------------
// Kernel A: convert emb f32 [V][128] -> fp16 table in ws. 77 MB streaming.
// ---------------------------------------------------------------------------
__global__ __launch_bounds__(256) void k_convert(const float* __restrict__ src,
                                                 __half* __restrict__ dst,
                                                 int n4) {
    int i = blockIdx.x * 256 + threadIdx.x;
    if (i >= n4) return;
    float4 v = ((const float4*)src)[i];
    union { __half2 h[2]; uint2 u; } pk;
    pk.h[0].x = __float2half_rn(v.x); pk.h[0].y = __float2half_rn(v.y);
    pk.h[1].x = __float2half_rn(v.z); pk.h[1].y = __float2half_rn(v.w);
    ((uint2*)dst)[i] = pk.u;
}

// ---------------------------------------------------------------------------
// Kernel B: convert W_cpr f32 [C][K] -> bf16 [C][K] (row-major, MFMA-native
// B operand layout: W16[n][k]). 128 KB out, ~0.5 us. No transpose needed.
// ---------------------------------------------------------------------------
__global__ __launch_bounds__(256) void k_convW(const float* __restrict__ src,
                                               __hip_bfloat16* __restrict__ dst) {
    int i = blockIdx.x * 256 + threadIdx.x;   // over float4s: 16384
    float4 v = ((const float4*)src)[i];
    union { __hip_bfloat16 b[4]; float2 f; } pk;
    pk.b[0] = __float2bfloat16(v.x); pk.b[1] = __float2bfloat16(v.y);
    pk.b[2] = __float2bfloat16(v.z); pk.b[3] = __float2bfloat16(v.w);
    ((float2*)dst)[i] = pk.f;
}

// ---------------------------------------------------------------------------
// Gather kernel (fp16 table): 1 batch row per WAVE, 4 waves/block, grid 2048.
// Same structure as R10 (compacted branch-free, 2x 1KB loads/iter at full
// residency); output X now written as bf16 (RNE) - MFMA A-operand ready.
// X16 row: [0..127]=left sum, [128..255]=right sum.
// ---------------------------------------------------------------------------
__global__ __launch_bounds__(256, 8) void k_gather_h(
    const int* __restrict__ ltok, const int* __restrict__ rtok,
    const int* __restrict__ lmask, const int* __restrict__ rmask,
    const __half* __restrict__ E16, __hip_bfloat16* __restrict__ X16) {

    __shared__ int ctok[4][2][52];

    const int wave = threadIdx.x >> 6;
    const int lane = threadIdx.x & 63;
    const int grp = lane >> 4;   // 16-lane group 0..3 (token slot within quad)
    const int sub = lane & 15;   // float4 slot within a 256 B fp16 row
    const int row = blockIdx.x * 4 + wave;

    int lt = 0, rt = 0, lm = 0, rm = 0;
    if (lane < L_SZ) {
        const size_t o = (size_t)row * L_SZ + lane;
        lt = ltok[o]; lm = lmask[o]; rt = rtok[o]; rm = rmask[o];
    }
    const unsigned long long ltm = (1ULL << lane) - 1;
    const unsigned long long balL = __ballot(lm != 0);
    const unsigned long long balR = __ballot(rm != 0);
    const int cntL = __popcll(balL);
    const int cntR = __popcll(balR);
    if (lm) ctok[wave][0][__popcll(balL & ltm)] = lt;
    if (rm) ctok[wave][1][__popcll(balR & ltm)] = rt;
    if (lane == 0) {
        if (cntL == 0) ctok[wave][0][0] = 0;
        if (cntR == 0) ctok[wave][1][0] = 0;
    }

    const float4* E = (const float4*)E16;  // [V][16] float4 (8 halves each)
    float aL[8] = {0}, aR[8] = {0};
    const int maxc = max(cntL, cntR);
    const int nit = (maxc + 3) >> 2;

    for (int it = 0; it < nit; ++it) {
        const int idx = it * 4 + grp;
#define GATH(side, cnt, A)                                                \
        {                                                                 \
            int ii = min(idx, cnt - 1); ii = (ii < 0) ? 0 : ii;           \
            const int t_ = ctok[wave][side][ii];                          \
            const float sc = (idx < cnt) ? 1.f : 0.f;                     \
            const float4 ev = E[((size_t)t_ << 4) + sub];                 \
            const __half2* hp = (const __half2*)&ev;                      \
            _Pragma("unroll")                                             \
            for (int q = 0; q < 4; ++q) {                                 \
                A[2 * q]     = fmaf(sc, __half2float(hp[q].x), A[2 * q]);       \
                A[2 * q + 1] = fmaf(sc, __half2float(hp[q].y), A[2 * q + 1]);   \
            }                                                             \
        }
        GATH(0, cntL, aL)
        GATH(1, cntR, aR)
#undef GATH
    }

#pragma unroll
    for (int j = 0; j < 8; ++j) {
        aL[j] += __shfl_xor(aL[j], 16);
        aL[j] += __shfl_xor(aL[j], 32);
        aR[j] += __shfl_xor(aR[j], 16);
        aR[j] += __shfl_xor(aR[j], 32);
    }

    // store as bf16: lane (grp, sub) owns dims [sub*8 .. sub*8+7] of its side
    union { __hip_bfloat16 b[8]; float4 v; } pk;
    if (grp == 0) {
#pragma unroll
        for (int j = 0; j < 8; ++j) pk.b[j] = __float2bfloat16(aL[j]);
        *(float4*)((char*)X16 + (size_t)row * 512 + sub * 16) = pk.v;
    } else if (grp == 1) {
#pragma unroll
        for (int j = 0; j < 8; ++j) pk.b[j] = __float2bfloat16(aR[j]);
        *(float4*)((char*)X16 + (size_t)row * 512 + 256 + sub * 16) = pk.v;
    }
}

// ---------------------------------------------------------------------------
// MLP kernel v4 (MFMA): h = LeakyReLU(X@W^T + b); logits = h@W_sm^T + b_sm;
// out = log_softmax.
// 256 threads = 4 waves; 32 rows/block; grid 256 (1 block/CU).
// Whole W16 staged in LDS [256 n][264 k] bf16 (135 KB; +8 pad -> 2-way banks,
// free). Wave (w>>1) takes row half, (w&1) takes col half: 1 Mtile x 8 Ntiles
// x 8 Ksteps of mfma_f32_16x16x32_bf16. A-frags (8) prefetched from global
// X16. h written back into the W LDS region (f32 [32][260]) for the head.
// Fragment layouts (m89-verified family): A/B: row|col=lane&15,
// k=(lane>>4)*8+j ; C/D: col=lane&15, row=(lane>>4)*4+reg.
// ---------------------------------------------------------------------------
__global__ __launch_bounds__(256) void k_mlp_mfma(
    const __hip_bfloat16* __restrict__ X16,
    const __hip_bfloat16* __restrict__ W16,
    const float* __restrict__ b_cpr, const float* __restrict__ W_sm,
    const float* __restrict__ b_sm, float* __restrict__ out) {

    __shared__ unsigned short Wl[256][264];   // 135168 B (bf16 bits)
    __shared__ float l_lds[32][R_SZ];

    const int tid = threadIdx.x;
    const int wave = tid >> 6;
    const int lane = tid & 63;
    const int row0 = blockIdx.x * 32;
    const int w_r = (wave >> 1) * 16;    // wave's row offset within block
    const int w_c = (wave & 1) * 128;    // wave's col offset

    // ---- A-frag prefetch: 8 ksteps, lane reads X16[row][k0..k0+7] ----
    bf16x8 av[8];
    {
        const int arow = row0 + w_r + (lane & 15);
        const int kbase = (lane >> 4) * 8;
#pragma unroll
        for (int ks = 0; ks < 8; ++ks)
            av[ks] = *(const bf16x8*)(X16 + (size_t)arow * K_SZ + ks * 32 + kbase);
    }

    // ---- stage whole W16 into LDS: 256 rows x 512 B, 32 chunks/row ----
    {
#pragma unroll
        for (int i = 0; i < 32; ++i) {
            const int flat = i * 256 + tid;       // 8192 chunks of 16 B
            const int n = flat >> 5;
            const int c = flat & 31;
            *(float4*)&Wl[n][c * 8] =
                *(const float4*)(W16 + (size_t)n * K_SZ + c * 8);
        }
    }
    __syncthreads();

    // ---- MFMA: 8 ksteps x 8 ntiles ----
    f32x4 acc[8];
#pragma unroll
    for (int nt = 0; nt < 8; ++nt) acc[nt] = (f32x4){0.f, 0.f, 0.f, 0.f};

    const int bl_n = lane & 15;
    const int bl_k = (lane >> 4) * 8;
#pragma unroll
    for (int ks = 0; ks < 8; ++ks) {
#pragma unroll
        for (int nt = 0; nt < 8; ++nt) {
            const bf16x8 bv =
                *(const bf16x8*)&Wl[w_c + nt * 16 + bl_n][ks * 32 + bl_k];
            acc[nt] = __builtin_amdgcn_mfma_f32_16x16x32_bf16(
                av[ks], bv, acc[nt], 0, 0, 0);
        }
    }
    __syncthreads();   // all B-frag reads done before h aliases Wl

    // ---- bias + LeakyReLU -> h (f32, aliased onto Wl region) ----
    float (*h_lds)[C_SZ + 4] = (float (*)[C_SZ + 4])&Wl[0][0];
    {
        const int hr = w_r + (lane >> 4) * 4;    // + j
        const int hcb = w_c + bl_n;              // + nt*16
#pragma unroll
        for (int nt = 0; nt < 8; ++nt) {
            const int col = hcb + nt * 16;
            const float b = b_cpr[col];
#pragma unroll
            for (int j = 0; j < 4; ++j) {
                float h = acc[nt][j] + b;
                h_lds[hr + j][col] = (h >= 0.f) ? h : 0.01f * h;
            }
        }
    }
    __syncthreads();

    // ---- head: 224 threads, one (row, r) dot of length 256 ----
    if (tid < 32 * R_SZ) {
        const int bl = tid / R_SZ;
        const int rh = tid % R_SZ;
        const float* wr = W_sm + rh * C_SZ;
        float s = b_sm[rh];
#pragma unroll 4
        for (int c = 0; c < C_SZ; c += 4) {
            float4 hv = *(const float4*)&h_lds[bl][c];
            s = fmaf(hv.x, wr[c + 0], s);
            s = fmaf(hv.y, wr[c + 1], s);
            s = fmaf(hv.z, wr[c + 2], s);
            s = fmaf(hv.w, wr[c + 3], s);
        }
        l_lds[bl][rh] = s;
    }
    __syncthreads();

    // ---- log-softmax over R=7 ----
    if (tid < 32) {
        float m = -INFINITY;
#pragma unroll
        for (int rh = 0; rh < R_SZ; ++rh) m = fmaxf(m, l_lds[tid][rh]);
        float se = 0.f;
#pragma unroll
        for (int rh = 0; rh < R_SZ; ++rh) se += expf(l_lds[tid][rh] - m);
        const float lse = m + logf(se);
        const size_t ob = (size_t)(row0 + tid) * R_SZ;
#pragma unroll
        for (int rh = 0; rh < R_SZ; ++rh) out[ob + rh] = l_lds[tid][rh] - lse;
    }
}

// ---------------------------------------------------------------------------
extern "C" void kernel_launch(void* const* d_in, const int* in_sizes, int n_in,
                              void* d_out, int out_size, void* d_ws, size_t ws_size,
                              hipStream_t stream) {
    const int* ltok = (const int*)d_in[0];
    const int* rtok = (const int*)d_in[1];
    const int* lmask = (const int*)d_in[2];
    const int* rmask = (const int*)d_in[3];
    const float* emb = (const float*)d_in[4];
    const float* W_cpr = (const float*)d_in[5];
    const float* b_cpr = (const float*)d_in[6];
    const float* W_sm = (const float*)d_in[7];
    const float* b_sm = (const float*)d_in[8];
    float* out = (float*)d_out;

    // ws layout (observed ws_size ~268 MB):
    //   E16  [V][128] fp16   25.6 MB
    //   W16  [256][256] bf16 128 KB
    //   X16  [B][256] bf16   4 MB
    const size_t E16_BYTES = (size_t)V_SZ * D_SZ * sizeof(__half);
    const size_t W16_BYTES = (size_t)C_SZ * K_SZ * sizeof(__hip_bfloat16);
    __half* E16 = (__half*)d_ws;
    __hip_bfloat16* W16 = (__hip_bfloat16*)((char*)d_ws + E16_BYTES);
    __hip_bfloat16* X16 =
        (__hip_bfloat16*)((char*)d_ws + E16_BYTES + W16_BYTES);

    const int n4 = V_SZ * D_SZ / 4;
    k_convW<<<(C_SZ * K_SZ / 4) / 256, 256, 0, stream>>>(W_cpr, W16);
    k_convert<<<(n4 + 255) / 256, 256, 0, stream>>>(emb, E16, n4);
    k_gather_h<<<B_SZ / 4, 256, 0, stream>>>(ltok, rtok, lmask, rmask,
                                             E16, X16);
    k_mlp_mfma<<<B_SZ / 32, 256, 0, stream>>>(X16, W16, b_cpr, W_sm,
                                              b_sm, out);
}

// Round 13
// 46.742 us; speedup vs baseline: 1.6572x; 1.0990x over previous
//
#include <hip/hip_runtime.h>
#include <hip/hip_fp16.h>
#include <hip/hip_bf16.h>
#include <math.h>

// Problem constants (from reference)
#define B_SZ 8192
#define L_SZ 50
#define D_SZ 128
#define C_SZ 256        // output cols of W_cpr
#define K_SZ 256        // = 2*D, GEMM K
#define R_SZ 7
#define V_SZ 100000

typedef __attribute__((ext_vector_type(8))) short bf16x8;
typedef __attribute__((ext_vector_type(4))) float f32x4;

#define EMB_N4 (V_SZ * D_SZ / 4)     // 3,200,000 float4s of emb
#define W_N4   (C_SZ * K_SZ / 4)     // 16,384 float4s of W_cpr

// ---------------------------------------------------------------------------
// Kernel A: fused dtype prep. First EMB_N4 threads convert emb f32->fp16;
// next W_N4 convert W_cpr f32->bf16 (row-major [n][k], MFMA B-ready).
// ---------------------------------------------------------------------------
__global__ __launch_bounds__(256) void k_conv(const float* __restrict__ emb,
                                              __half* __restrict__ E16,
                                              const float* __restrict__ W,
                                              __hip_bfloat16* __restrict__ W16) {
    int i = blockIdx.x * 256 + threadIdx.x;
    if (i < EMB_N4) {
        float4 v = ((const float4*)emb)[i];
        union { __half2 h[2]; uint2 u; } pk;
        pk.h[0].x = __float2half_rn(v.x); pk.h[0].y = __float2half_rn(v.y);
        pk.h[1].x = __float2half_rn(v.z); pk.h[1].y = __float2half_rn(v.w);
        ((uint2*)E16)[i] = pk.u;
    } else if (i < EMB_N4 + W_N4) {
        const int j = i - EMB_N4;
        float4 v = ((const float4*)W)[j];
        union { __hip_bfloat16 b[4]; float2 f; } pk;
        pk.b[0] = __float2bfloat16(v.x); pk.b[1] = __float2bfloat16(v.y);
        pk.b[2] = __float2bfloat16(v.z); pk.b[3] = __float2bfloat16(v.w);
        ((float2*)W16)[j] = pk.f;
    }
}

// ---------------------------------------------------------------------------
// Gather kernel (fp16 table): 1 batch row per WAVE, 4 waves/block, grid 2048
// (32 waves/CU residency). Per iteration: FOUR independent unconditional
// 1 KB row-loads in one basic block (8 tokens/side) -> 4 KB in flight/wave,
// 2x R12's issue depth. Compacted token lists in LDS; pad slots re-read a
// clamped index with scale 0 (L1 hits). Output X in bf16 (MFMA A-ready).
// ---------------------------------------------------------------------------
__global__ __launch_bounds__(256, 8) void k_gather_h(
    const int* __restrict__ ltok, const int* __restrict__ rtok,
    const int* __restrict__ lmask, const int* __restrict__ rmask,
    const __half* __restrict__ E16, __hip_bfloat16* __restrict__ X16) {

    __shared__ int ctok[4][2][52];

    const int wave = threadIdx.x >> 6;
    const int lane = threadIdx.x & 63;
    const int grp = lane >> 4;   // 16-lane group 0..3 (token slot)
    const int sub = lane & 15;   // float4 slot within a 256 B fp16 row
    const int row = blockIdx.x * 4 + wave;

    int lt = 0, rt = 0, lm = 0, rm = 0;
    if (lane < L_SZ) {
        const size_t o = (size_t)row * L_SZ + lane;
        lt = ltok[o]; lm = lmask[o]; rt = rtok[o]; rm = rmask[o];
    }
    const unsigned long long ltm = (1ULL << lane) - 1;
    const unsigned long long balL = __ballot(lm != 0);
    const unsigned long long balR = __ballot(rm != 0);
    const int cntL = __popcll(balL);
    const int cntR = __popcll(balR);
    if (lm) ctok[wave][0][__popcll(balL & ltm)] = lt;
    if (rm) ctok[wave][1][__popcll(balR & ltm)] = rt;
    if (lane == 0) {
        if (cntL == 0) ctok[wave][0][0] = 0;
        if (cntR == 0) ctok[wave][1][0] = 0;
    }

    const float4* E = (const float4*)E16;  // [V][16] float4 (8 halves each)
    float aL[8] = {0}, aR[8] = {0};
    const int maxc = max(cntL, cntR);
    const int nit = (maxc + 7) >> 3;       // 8 tokens/side per iteration

    for (int it = 0; it < nit; ++it) {
        const int idxA = it * 8 + grp;
        const int idxB = it * 8 + 4 + grp;
        // --- issue all four 1 KB loads first (independent, one BB) ---
        int iiA0 = min(idxA, cntL - 1); iiA0 = (iiA0 < 0) ? 0 : iiA0;
        int iiB0 = min(idxB, cntL - 1); iiB0 = (iiB0 < 0) ? 0 : iiB0;
        int iiA1 = min(idxA, cntR - 1); iiA1 = (iiA1 < 0) ? 0 : iiA1;
        int iiB1 = min(idxB, cntR - 1); iiB1 = (iiB1 < 0) ? 0 : iiB1;
        const int tA0 = ctok[wave][0][iiA0];
        const int tB0 = ctok[wave][0][iiB0];
        const int tA1 = ctok[wave][1][iiA1];
        const int tB1 = ctok[wave][1][iiB1];
        const float4 eA0 = E[((size_t)tA0 << 4) + sub];
        const float4 eB0 = E[((size_t)tB0 << 4) + sub];
        const float4 eA1 = E[((size_t)tA1 << 4) + sub];
        const float4 eB1 = E[((size_t)tB1 << 4) + sub];
        const float sA0 = (idxA < cntL) ? 1.f : 0.f;
        const float sB0 = (idxB < cntL) ? 1.f : 0.f;
        const float sA1 = (idxA < cntR) ? 1.f : 0.f;
        const float sB1 = (idxB < cntR) ? 1.f : 0.f;
        // --- accumulate ---
#define ACC8(A, ev, sc)                                                   \
        {                                                                 \
            const __half2* hp = (const __half2*)&ev;                      \
            _Pragma("unroll")                                             \
            for (int q = 0; q < 4; ++q) {                                 \
                A[2 * q]     = fmaf(sc, __half2float(hp[q].x), A[2 * q]);       \
                A[2 * q + 1] = fmaf(sc, __half2float(hp[q].y), A[2 * q + 1]);   \
            }                                                             \
        }
        ACC8(aL, eA0, sA0)
        ACC8(aL, eB0, sB0)
        ACC8(aR, eA1, sA1)
        ACC8(aR, eB1, sB1)
#undef ACC8
    }

#pragma unroll
    for (int j = 0; j < 8; ++j) {
        aL[j] += __shfl_xor(aL[j], 16);
        aL[j] += __shfl_xor(aL[j], 32);
        aR[j] += __shfl_xor(aR[j], 16);
        aR[j] += __shfl_xor(aR[j], 32);
    }

    // store as bf16: lane (grp, sub) owns dims [sub*8 .. sub*8+7] of its side
    union { __hip_bfloat16 b[8]; float4 v; } pk;
    if (grp == 0) {
#pragma unroll
        for (int j = 0; j < 8; ++j) pk.b[j] = __float2bfloat16(aL[j]);
        *(float4*)((char*)X16 + (size_t)row * 512 + sub * 16) = pk.v;
    } else if (grp == 1) {
#pragma unroll
        for (int j = 0; j < 8; ++j) pk.b[j] = __float2bfloat16(aR[j]);
        *(float4*)((char*)X16 + (size_t)row * 512 + 256 + sub * 16) = pk.v;
    }
}

// ---------------------------------------------------------------------------
// MLP kernel v5 (MFMA, 512 thr): h = LeakyReLU(X@W^T + b);
// logits = h@W_sm^T + b_sm; out = log_softmax.
// 8 waves; wave (w>>2) takes 16-row half, (w&3) takes 64-col quarter:
// 4 ntiles x 8 ksteps = 32 mfma_f32_16x16x32_bf16 per wave. Whole W16 in
// LDS [256][264] bf16 (135 KB, +8 pad). A-frags prefetched from global X16.
// h (f32) aliased onto the W LDS region for the head.
// Layouts (m89-verified): A/B: row|col=lane&15, k=(lane>>4)*8+j ;
// C/D: col=lane&15, row=(lane>>4)*4+reg.
// ---------------------------------------------------------------------------
__global__ __launch_bounds__(512) void k_mlp_mfma(
    const __hip_bfloat16* __restrict__ X16,
    const __hip_bfloat16* __restrict__ W16,
    const float* __restrict__ b_cpr, const float* __restrict__ W_sm,
    const float* __restrict__ b_sm, float* __restrict__ out) {

    __shared__ unsigned short Wl[256][264];   // 135168 B (bf16 bits)
    __shared__ float l_lds[32][R_SZ];

    const int tid = threadIdx.x;
    const int wave = tid >> 6;
    const int lane = tid & 63;
    const int row0 = blockIdx.x * 32;
    const int w_r = (wave >> 2) * 16;    // wave's row offset (0 or 16)
    const int w_c = (wave & 3) * 64;     // wave's col offset (0/64/128/192)

    // ---- A-frag prefetch: 8 ksteps, lane reads X16[row][k0..k0+7] ----
    bf16x8 av[8];
    {
        const int arow = row0 + w_r + (lane & 15);
        const int kbase = (lane >> 4) * 8;
#pragma unroll
        for (int ks = 0; ks < 8; ++ks)
            av[ks] = *(const bf16x8*)(X16 + (size_t)arow * K_SZ + ks * 32 + kbase);
    }

    // ---- stage whole W16 into LDS: 8192 16B-chunks, 16 per thread ----
    {
#pragma unroll
        for (int i = 0; i < 16; ++i) {
            const int flat = i * 512 + tid;
            const int n = flat >> 5;
            const int c = flat & 31;
            *(float4*)&Wl[n][c * 8] =
                *(const float4*)(W16 + (size_t)n * K_SZ + c * 8);
        }
    }
    __syncthreads();

    // ---- MFMA: 8 ksteps x 4 ntiles per wave ----
    f32x4 acc[4];
#pragma unroll
    for (int nt = 0; nt < 4; ++nt) acc[nt] = (f32x4){0.f, 0.f, 0.f, 0.f};

    const int bl_n = lane & 15;
    const int bl_k = (lane >> 4) * 8;
#pragma unroll
    for (int ks = 0; ks < 8; ++ks) {
#pragma unroll
        for (int nt = 0; nt < 4; ++nt) {
            const bf16x8 bv =
                *(const bf16x8*)&Wl[w_c + nt * 16 + bl_n][ks * 32 + bl_k];
            acc[nt] = __builtin_amdgcn_mfma_f32_16x16x32_bf16(
                av[ks], bv, acc[nt], 0, 0, 0);
        }
    }
    __syncthreads();   // all B-frag reads done before h aliases Wl

    // ---- bias + LeakyReLU -> h (f32, aliased onto Wl region) ----
    float (*h_lds)[C_SZ + 4] = (float (*)[C_SZ + 4])&Wl[0][0];
    {
        const int hr = w_r + (lane >> 4) * 4;    // + j
        const int hcb = w_c + bl_n;              // + nt*16
#pragma unroll
        for (int nt = 0; nt < 4; ++nt) {
            const int col = hcb + nt * 16;
            const float b = b_cpr[col];
#pragma unroll
            for (int j = 0; j < 4; ++j) {
                float h = acc[nt][j] + b;
                h_lds[hr + j][col] = (h >= 0.f) ? h : 0.01f * h;
            }
        }
    }
    __syncthreads();

    // ---- head: 224 threads, one (row, r) dot of length 256 ----
    if (tid < 32 * R_SZ) {
        const int bl = tid / R_SZ;
        const int rh = tid % R_SZ;
        const float* wr = W_sm + rh * C_SZ;
        float s = b_sm[rh];
#pragma unroll 4
        for (int c = 0; c < C_SZ; c += 4) {
            float4 hv = *(const float4*)&h_lds[bl][c];
            s = fmaf(hv.x, wr[c + 0], s);
            s = fmaf(hv.y, wr[c + 1], s);
            s = fmaf(hv.z, wr[c + 2], s);
            s = fmaf(hv.w, wr[c + 3], s);
        }
        l_lds[bl][rh] = s;
    }
    __syncthreads();

    // ---- log-softmax over R=7 ----
    if (tid < 32) {
        float m = -INFINITY;
#pragma unroll
        for (int rh = 0; rh < R_SZ; ++rh) m = fmaxf(m, l_lds[tid][rh]);
        float se = 0.f;
#pragma unroll
        for (int rh = 0; rh < R_SZ; ++rh) se += expf(l_lds[tid][rh] - m);
        const float lse = m + logf(se);
        const size_t ob = (size_t)(row0 + tid) * R_SZ;
#pragma unroll
        for (int rh = 0; rh < R_SZ; ++rh) out[ob + rh] = l_lds[tid][rh] - lse;
    }
}

// ---------------------------------------------------------------------------
extern "C" void kernel_launch(void* const* d_in, const int* in_sizes, int n_in,
                              void* d_out, int out_size, void* d_ws, size_t ws_size,
                              hipStream_t stream) {
    const int* ltok = (const int*)d_in[0];
    const int* rtok = (const int*)d_in[1];
    const int* lmask = (const int*)d_in[2];
    const int* rmask = (const int*)d_in[3];
    const float* emb = (const float*)d_in[4];
    const float* W_cpr = (const float*)d_in[5];
    const float* b_cpr = (const float*)d_in[6];
    const float* W_sm = (const float*)d_in[7];
    const float* b_sm = (const float*)d_in[8];
    float* out = (float*)d_out;

    // ws layout: E16 [V][128] fp16 (25.6 MB) | W16 [256][256] bf16 (128 KB)
    //            | X16 [B][256] bf16 (4 MB)
    const size_t E16_BYTES = (size_t)V_SZ * D_SZ * sizeof(__half);
    const size_t W16_BYTES = (size_t)C_SZ * K_SZ * sizeof(__hip_bfloat16);
    __half* E16 = (__half*)d_ws;
    __hip_bfloat16* W16 = (__hip_bfloat16*)((char*)d_ws + E16_BYTES);
    __hip_bfloat16* X16 =
        (__hip_bfloat16*)((char*)d_ws + E16_BYTES + W16_BYTES);

    const int nconv = EMB_N4 + W_N4;
    k_conv<<<(nconv + 255) / 256, 256, 0, stream>>>(emb, E16, W_cpr, W16);
    k_gather_h<<<B_SZ / 4, 256, 0, stream>>>(ltok, rtok, lmask, rmask,
                                             E16, X16);
    k_mlp_mfma<<<B_SZ / 32, 512, 0, stream>>>(X16, W16, b_cpr, W_sm,
                                              b_sm, out);
}